// Round 3
// baseline (1072.969 us; speedup 1.0000x reference)
//
#include <hip/hip_runtime.h>
#include <cmath>

#define NLEV 16
#define TPB 256

typedef float v4f __attribute__((ext_vector_type(4)));
typedef float v2f __attribute__((ext_vector_type(2)));

// Level metadata replicated from the reference's _level_meta() (float64 host
// math; boundary levels 5/10/15 land 1e-5 ABOVE the integer -> res=65/257/1025).
static constexpr unsigned kRes[NLEV] = {16u,22u,28u,37u,49u,65u,85u,112u,148u,195u,257u,338u,446u,589u,777u,1025u};
static constexpr unsigned kMsz[NLEV] = {4096u,10648u,21952u,50656u,117656u,274632u,
  524288u,524288u,524288u,524288u,524288u,524288u,524288u,524288u,524288u,524288u};
static constexpr unsigned kOff[NLEV] = {0u,4096u,14744u,36696u,87352u,205008u,479640u,1003928u,
  1528216u,2052504u,2576792u,3101080u,3625368u,4149656u,4673944u,5198232u};
static constexpr int kDense[NLEV] = {1,1,1,1,1,1,0,0,0,0,0,0,0,0,0,0};

struct ScaleParams { float s[NLEV]; };

// ---------------------------------------------------------------------------
// DENSE: exact round-0 structure. No sched_barrier anywhere in the level loop:
// the compiler software-pipelines level L+1 gathers under level L FMAs, which
// is what made this kernel 230us. (Round-2's per-level sched_barrier(0)
// serialized the levels -> 425us. Reverted.)
// ---------------------------------------------------------------------------

__device__ __forceinline__ void load_pos(const float* __restrict__ pos, float* sp,
                                         int tid, size_t pbase,
                                         float& px, float& py, float& pz) {
  const float* src = pos + pbase * 3;
  sp[tid]       = __builtin_nontemporal_load(src + tid);
  sp[tid + 256] = __builtin_nontemporal_load(src + tid + 256);
  sp[tid + 512] = __builtin_nontemporal_load(src + tid + 512);
  __syncthreads();
  px = sp[tid*3 + 0]; py = sp[tid*3 + 1]; pz = sp[tid*3 + 2];
}

__global__ __launch_bounds__(TPB, 4) void dense_levels(
    const float* __restrict__ pos, const float* __restrict__ table,
    float* __restrict__ ws, ScaleParams spar, int npts)
{
  __shared__ float sp[TPB * 3];
  const int tid = threadIdx.x;
  const size_t pbase = (size_t)blockIdx.x * TPB;
  float px, py, pz;
  load_pos(pos, sp, tid, pbase, px, py, pz);

  const float2* __restrict__ tab2 = (const float2*)table;
#pragma unroll
  for (int L = 0; L < 6; ++L) {
    const float scale = spar.s[L];
    const float x = px * scale + 0.5f;
    const float y = py * scale + 0.5f;
    const float z = pz * scale + 0.5f;
    const float xf = floorf(x), yf = floorf(y), zf = floorf(z);
    const float tx = x - xf, ty = y - yf, tz = z - zf;
    const unsigned xi = (unsigned)xf, yi = (unsigned)yf, zi = (unsigned)zf;

    const unsigned r = kRes[L];
    const unsigned hx[2] = {xi, xi + 1u};
    const unsigned hy[2] = {yi * r, (yi + 1u) * r};
    const unsigned hz[2] = {zi * r * r, (zi + 1u) * r * r};
    const float wx[2] = {1.0f - tx, tx};
    const float wy[2] = {1.0f - ty, ty};
    const float wz[2] = {1.0f - tz, tz};

    float a0 = 0.0f, a1 = 0.0f;
#pragma unroll
    for (int c = 0; c < 8; ++c) {
      // h < 2*msize provably (h <= r*(1+r+r^2) < 2*r^3 <= 2*msize)
      const unsigned h = hx[c & 1] + hy[(c >> 1) & 1] + hz[(c >> 2) & 1];
      const unsigned idx = (h >= kMsz[L]) ? (h - kMsz[L]) : h;
      const float2 f = tab2[kOff[L] + idx];
      const float w = wx[c & 1] * wy[(c >> 1) & 1] * wz[(c >> 2) & 1];
      a0 = fmaf(w, f.x, a0);
      a1 = fmaf(w, f.y, a1);
    }
    v2f rr; rr.x = a0; rr.y = a1;
    __builtin_nontemporal_store(rr, (v2f*)ws + (size_t)L * npts + pbase + tid);
  }
}

// ---------------------------------------------------------------------------
// HASH: 4 points/thread. Issue all 32 gathers, then compute weights (VALU work
// between issue and consume), then accumulate. One sched_barrier after the
// load group (single-level kernel -> no cross-level pipelining to destroy).
// ---------------------------------------------------------------------------

__global__ __launch_bounds__(TPB, 4) void hash_fused4(
    const float* __restrict__ pos, const float* __restrict__ table,
    float* __restrict__ ws, ScaleParams spar, int lvlShift, int npts)
{
  __shared__ float sp[TPB * 12];
  const int tid = threadIdx.x;
  const int lvl = 6 + (int)(blockIdx.x >> lvlShift);
  const unsigned pb = blockIdx.x & ((1u << lvlShift) - 1u);

  // uniform scalar select of this block's scale (avoids dynamic kernarg index)
  float scale = 0.0f;
#pragma unroll
  for (int l = 6; l < NLEV; ++l) if (l == lvl) scale = spar.s[l];
  const unsigned off = kOff[6] + (unsigned)(lvl - 6) * 524288u;

  const size_t pbase = (size_t)pb * (TPB * 4);
  {
    const float* src = pos + pbase * 3;
#pragma unroll
    for (int k = 0; k < 12; ++k)
      sp[tid + k * TPB] = __builtin_nontemporal_load(src + tid + k * TPB);
    __syncthreads();
  }

  float frac[4][3];
  unsigned idx[4][8];
#pragma unroll
  for (int p = 0; p < 4; ++p) {
    const float x = sp[tid*12 + p*3 + 0] * scale + 0.5f;
    const float y = sp[tid*12 + p*3 + 1] * scale + 0.5f;
    const float z = sp[tid*12 + p*3 + 2] * scale + 0.5f;
    const float xf = floorf(x), yf = floorf(y), zf = floorf(z);
    frac[p][0] = x - xf; frac[p][1] = y - yf; frac[p][2] = z - zf;
    const unsigned xi = (unsigned)xf, yi = (unsigned)yf, zi = (unsigned)zf;
    const unsigned hx[2] = {xi, xi + 1u};
    const unsigned hy[2] = {yi * 2654435761u, (yi + 1u) * 2654435761u};
    const unsigned hz[2] = {zi * 805459861u,  (zi + 1u) * 805459861u};
#pragma unroll
    for (int c = 0; c < 8; ++c)
      idx[p][c] = (hx[c & 1] ^ hy[(c >> 1) & 1] ^ hz[(c >> 2) & 1]) & 524287u;
  }

  // Batch-issue all 32 gathers.
  const v2f* __restrict__ t2 = (const v2f*)table + off;
  v2f f[4][8];
#pragma unroll
  for (int p = 0; p < 4; ++p)
#pragma unroll
    for (int c = 0; c < 8; ++c)
      f[p][c] = t2[idx[p][c]];
  __builtin_amdgcn_sched_barrier(0);   // loads must be issued before anything below

  // Weight computation overlaps gather latency.
  float w[4][8];
#pragma unroll
  for (int p = 0; p < 4; ++p) {
    const float wx[2] = {1.0f - frac[p][0], frac[p][0]};
    const float wy[2] = {1.0f - frac[p][1], frac[p][1]};
    const float wz[2] = {1.0f - frac[p][2], frac[p][2]};
#pragma unroll
    for (int c = 0; c < 8; ++c)
      w[p][c] = wx[c & 1] * wy[(c >> 1) & 1] * wz[(c >> 2) & 1];
  }

  float acc[4][2];
#pragma unroll
  for (int p = 0; p < 4; ++p) {
    float a0 = 0.0f, a1 = 0.0f;
#pragma unroll
    for (int c = 0; c < 8; ++c) {
      a0 = fmaf(w[p][c], f[p][c].x, a0);
      a1 = fmaf(w[p][c], f[p][c].y, a1);
    }
    acc[p][0] = a0; acc[p][1] = a1;
  }

  // ws layout: v2f entry (lvl*npts + point); points p = pbase + 4*tid + {0..3}.
  v4f* dst = (v4f*)ws + ((size_t)lvl * npts + pbase) / 2 + 2 * tid;
  v4f v0; v0.x = acc[0][0]; v0.y = acc[0][1]; v0.z = acc[1][0]; v0.w = acc[1][1];
  v4f v1; v1.x = acc[2][0]; v1.y = acc[2][1]; v1.z = acc[3][0]; v1.w = acc[3][1];
  __builtin_nontemporal_store(v0, dst);
  __builtin_nontemporal_store(v1, dst + 1);
}

__global__ __launch_bounds__(TPB, 4) void transpose_out(
    const float* __restrict__ ws, float* __restrict__ out, int npts)
{
  __shared__ float lds[TPB * 33];
  const int tid = threadIdx.x;
  const size_t pbase = (size_t)blockIdx.x * TPB;
#pragma unroll
  for (int L = 0; L < NLEV; ++L) {
    const v2f w = __builtin_nontemporal_load((const v2f*)ws + (size_t)L * npts + pbase + tid);
    lds[tid * 33 + 2 * L]     = w.x;
    lds[tid * 33 + 2 * L + 1] = w.y;
  }
  __syncthreads();
  v4f* out4 = (v4f*)out + (size_t)blockIdx.x * (TPB * 32 / 4);
#pragma unroll
  for (int k = 0; k < 8; ++k) {
    const int q  = tid + k * TPB;
    const int p  = q >> 3;
    const int c4 = (q & 7) * 4;
    v4f v;
    v.x = lds[p * 33 + c4 + 0];
    v.y = lds[p * 33 + c4 + 1];
    v.z = lds[p * 33 + c4 + 2];
    v.w = lds[p * 33 + c4 + 3];
    __builtin_nontemporal_store(v, out4 + q);
  }
}

// ---------------------------------------------------------------------------
// Fallback monolithic kernel (proven correct) if ws is too small or the grid
// geometry assumptions don't hold.
// ---------------------------------------------------------------------------
__global__ __launch_bounds__(TPB) void hashenc_kernel(
    const float* __restrict__ pos, const float* __restrict__ table,
    float* __restrict__ out, ScaleParams spar)
{
  __shared__ float lds[TPB * 33];
  const int tid = threadIdx.x;
  const size_t pbase = (size_t)blockIdx.x * TPB;
  {
    const float* src = pos + pbase * 3;
    lds[tid]        = src[tid];
    lds[tid + 256]  = src[tid + 256];
    lds[tid + 512]  = src[tid + 512];
  }
  __syncthreads();
  const float px = lds[tid*3 + 0];
  const float py = lds[tid*3 + 1];
  const float pz = lds[tid*3 + 2];
  __syncthreads();

  const float2* __restrict__ tab2 = (const float2*)table;
  float acc[2 * NLEV];

#pragma unroll
  for (int L = 0; L < NLEV; ++L) {
    const float scale = spar.s[L];
    const float x = px * scale + 0.5f;
    const float y = py * scale + 0.5f;
    const float z = pz * scale + 0.5f;
    const float xf = floorf(x), yf = floorf(y), zf = floorf(z);
    const float tx = x - xf, ty = y - yf, tz = z - zf;
    const unsigned xi = (unsigned)xf, yi = (unsigned)yf, zi = (unsigned)zf;

    unsigned hx[2], hy[2], hz[2];
    if (kDense[L]) {
      const unsigned r = kRes[L];
      hx[0] = xi;          hx[1] = xi + 1u;
      hy[0] = yi * r;      hy[1] = (yi + 1u) * r;
      hz[0] = zi * r * r;  hz[1] = (zi + 1u) * r * r;
    } else {
      hx[0] = xi;                 hx[1] = xi + 1u;
      hy[0] = yi * 2654435761u;   hy[1] = (yi + 1u) * 2654435761u;
      hz[0] = zi * 805459861u;    hz[1] = (zi + 1u) * 805459861u;
    }
    const float wx[2] = {1.0f - tx, tx};
    const float wy[2] = {1.0f - ty, ty};
    const float wz[2] = {1.0f - tz, tz};

    float a0 = 0.0f, a1 = 0.0f;
#pragma unroll
    for (int c = 0; c < 8; ++c) {
      unsigned idx;
      if (kDense[L]) {
        unsigned h = hx[c & 1] + hy[(c >> 1) & 1] + hz[(c >> 2) & 1];
        idx = (h >= kMsz[L]) ? (h - kMsz[L]) : h;
      } else {
        idx = (hx[c & 1] ^ hy[(c >> 1) & 1] ^ hz[(c >> 2) & 1]) & (kMsz[L] - 1u);
      }
      const float2 f = tab2[kOff[L] + idx];
      const float w = wx[c & 1] * wy[(c >> 1) & 1] * wz[(c >> 2) & 1];
      a0 = fmaf(w, f.x, a0);
      a1 = fmaf(w, f.y, a1);
    }
    acc[2 * L]     = a0;
    acc[2 * L + 1] = a1;
  }

#pragma unroll
  for (int c = 0; c < 32; ++c) lds[tid * 33 + c] = acc[c];
  __syncthreads();

  v4f* out4 = (v4f*)out + (size_t)blockIdx.x * (TPB * 32 / 4);
#pragma unroll
  for (int k = 0; k < 8; ++k) {
    const int q  = tid + k * TPB;
    const int p  = q >> 3;
    const int c4 = (q & 7) * 4;
    v4f v;
    v.x = lds[p * 33 + c4 + 0];
    v.y = lds[p * 33 + c4 + 1];
    v.z = lds[p * 33 + c4 + 2];
    v.w = lds[p * 33 + c4 + 3];
    __builtin_nontemporal_store(v, out4 + q);
  }
}

extern "C" void kernel_launch(void* const* d_in, const int* in_sizes, int n_in,
                              void* d_out, int out_size, void* d_ws, size_t ws_size,
                              hipStream_t stream) {
  const float* pos   = (const float*)d_in[0];
  const float* table = (const float*)d_in[1];
  float* out = (float*)d_out;

  ScaleParams sp;
  for (int i = 0; i < NLEV; ++i)
    sp.s[i] = (float)(16.0 * exp((double)i * log(1.3195079565048218)) - 1.0);

  const int npts = in_sizes[0] / 3;   // 2097152
  const size_t need = (size_t)npts * 32 * sizeof(float);

  const int nq = npts / (TPB * 4);               // hash blocks per level (4 pts/thread)
  int sh = 0; while ((1 << sh) < nq) ++sh;
  const bool ok = (npts % (TPB * 4) == 0) && ((1 << sh) == nq);

  if (ws_size >= need && ok) {
    float* wsf = (float*)d_ws;
    dense_levels<<<npts / TPB, TPB, 0, stream>>>(pos, table, wsf, sp, npts);
    hash_fused4<<<nq * 10, TPB, 0, stream>>>(pos, table, wsf, sp, sh, npts);
    transpose_out<<<npts / TPB, TPB, 0, stream>>>(wsf, out, npts);
  } else {
    hashenc_kernel<<<npts / TPB, TPB, 0, stream>>>(pos, table, out, sp);
  }
}